// Round 5
// baseline (484.510 us; speedup 1.0000x reference)
//
#include <hip/hip_runtime.h>
#include <hip/hip_bf16.h>

#define BS_   2048
#define HID_  512
#define PH_   32

// s_getreg: size=4 bits (sz-1=3), offset=0, id=20 (HW_REG_XCC_ID, m09-verified)
#define HWREG_XCC_ID ((3 << 11) | (0 << 6) | 20)

// control-int layout inside cnt[]:
//   [0..255]   step counters: cnt[ib*32 + t], ib in [0,8)
//   [256..263] per-group XCD mask
//   [264..271] xslot[8] (per-XCD claim counters)
//   [272]      spillidx
//   [288..289] grid-sync counters
//   [320..575] taken[256] claim flags
#define C_STEP  0
#define C_MASK  256
#define C_SLOT  264
#define C_SPILL 272
#define C_GSYNC 288
#define C_TAKEN 320
#define C_TOTAL 576

typedef _Float16 half8 __attribute__((ext_vector_type(8)));
typedef float floatx4 __attribute__((ext_vector_type(4)));

__device__ __forceinline__ float sigf(float x) { return 1.f / (1.f + __expf(-x)); }
__device__ __forceinline__ float tanhfast(float x) {
    float e = __expf(2.f * x);          // e=inf -> 1, e->0 -> -1 : safe at extremes
    return 1.f - 2.f / (e + 1.f);
}

// ---------------------------------------------------------------------------
__global__ __launch_bounds__(256) void prep_kernel(
    const float* __restrict__ Wih, const float* __restrict__ Whh,
    const float* __restrict__ bih, const float* __restrict__ bhh,
    const float* __restrict__ z,
    _Float16* __restrict__ wih16, _Float16* __restrict__ wsum16,
    _Float16* __restrict__ z16, float* __restrict__ bsum,
    int* __restrict__ cnt)
{
    int i = blockIdx.x * 256 + threadIdx.x;          // [0, 1048576)
    if (i < BS_ * HID_) z16[i] = (_Float16)z[i];
    if (i < 4 * HID_ * HID_) {
        float a = Wih[i];
        wih16[i]  = (_Float16)a;
        wsum16[i] = (_Float16)(a + Whh[i]);
    }
    if (i < 4 * HID_) bsum[i] = bih[i] + bhh[i];
    if (i < C_TOTAL) cnt[i] = 0;
}

// ---------------------------------------------------------------------------
// Hand-rolled grid barrier for the cooperative kernel (used twice, distinct
// counters). Producer release = __threadfence (wbl2); consumer = RMW poll at
// the coherence point (R2 lesson: plain acquire loads go stale) + agent
// acquire fence (buffer_inv) so cross-XCD plain data (taken[]) is readable.
// ---------------------------------------------------------------------------
__device__ __forceinline__ void grid_sync(int* gc, int tid) {
    __syncthreads();
    if (tid == 0) {
        __threadfence();
        atomicAdd(gc, 1);
        while (__hip_atomic_fetch_add(gc, 0, __ATOMIC_RELAXED,
                                      __HIP_MEMORY_SCOPE_AGENT) < 256) {
            __builtin_amdgcn_s_sleep(1);
        }
        __builtin_amdgcn_fence(__ATOMIC_ACQUIRE, "agent");
    }
    __syncthreads();
}

__device__ __forceinline__ void stage_weights(_Float16* Wl, const _Float16* Wg,
                                              int j, int tid)
{
#pragma unroll
    for (int rep = 0; rep < 8; ++rep) {
        int idx = rep * 512 + tid;      // [0, 4096) over (row n, 16B-block kb)
        int n  = idx >> 6;
        int kb = idx & 63;
        int g  = n >> 4, u = n & 15;
        const half8* src = (const half8*)(Wg + ((size_t)(g * HID_ + j * 16 + u)) * HID_ + kb * 8);
        int phys = (kb & 56) | ((kb & 7) ^ (n & 7));
        *(half8*)((char*)Wl + n * 1024 + phys * 16) = *src;
    }
}

// ---------------------------------------------------------------------------
// Persistent LSTM. Grid = 256 x 512. Work (ib, j) is assigned DYNAMICALLY:
// each block claims a slot on its own physical XCD -> the 32 blocks of a
// group (one ib = 256 batch rows) share one coherent L2 by construction.
// Spill blocks (XCD got >32) take leftover slots after a grid barrier; any
// group they land in shows popcount(mask)>1 and runs the fenced protocol.
// kk-loop is software-pipelined: depth-4 A ring from global, double-buffered
// B from LDS; bias pre-folded into the accumulators.
// ---------------------------------------------------------------------------
__global__ __launch_bounds__(512, 2) void lstm_persist(
    const _Float16* __restrict__ wih16, const _Float16* __restrict__ wsum16,
    const float* __restrict__ bsum, const _Float16* __restrict__ z16,
    _Float16* __restrict__ hs, int* __restrict__ cnt)
{
    __shared__ _Float16 Wl[64 * 512];   // 64 KB
    __shared__ int sh_ctrl;

    const int tid  = threadIdx.x;
    const int lane = tid & 63;
    const int wv   = tid >> 6;          // wave 0..7 -> M strip of 32 rows
    const int qw   = lane >> 4;         // quad 0..3
    const int ln   = lane & 15;

    // ---- dynamic (ib, j) assignment on physical XCDs ----
    int x = 0, mine = -1, rank = -1;
    if (tid == 0) {
        x = __builtin_amdgcn_s_getreg(HWREG_XCC_ID) & 7;
        int s = __hip_atomic_fetch_add(&cnt[C_SLOT + x], 1, __ATOMIC_RELAXED,
                                       __HIP_MEMORY_SCOPE_AGENT);
        if (s < 32) {
            mine = x * 32 + s;
            cnt[C_TAKEN + mine] = 1;    // plain store; released by grid_sync
            __hip_atomic_fetch_or(&cnt[C_MASK + x], 1 << x, __ATOMIC_RELAXED,
                                  __HIP_MEMORY_SCOPE_AGENT);
        } else {
            rank = __hip_atomic_fetch_add(&cnt[C_SPILL], 1, __ATOMIC_RELAXED,
                                          __HIP_MEMORY_SCOPE_AGENT);
        }
    }
    grid_sync(&cnt[C_GSYNC + 0], tid);
    if (tid == 0 && mine < 0) {
        int seen = 0;
        for (int s = 0; s < 256; ++s) {
            if (cnt[C_TAKEN + s] == 0) {
                if (seen == rank) { mine = s; break; }
                ++seen;
            }
        }
        __hip_atomic_fetch_or(&cnt[C_MASK + (mine >> 5)], 1 << x,
                              __ATOMIC_RELAXED, __HIP_MEMORY_SCOPE_AGENT);
    }
    grid_sync(&cnt[C_GSYNC + 1], tid);
    if (tid == 0) {
        int m = __hip_atomic_fetch_add(&cnt[C_MASK + (mine >> 5)], 0,
                                       __ATOMIC_RELAXED, __HIP_MEMORY_SCOPE_AGENT);
        int fastf = (__popc((unsigned)m) == 1) ? 1 : 0;
        sh_ctrl = mine | (fastf << 16);
    }
    __syncthreads();
    const int ctrl = sh_ctrl;
    const int ib   = (ctrl & 0xffff) >> 5;
    const int j    = ctrl & 31;
    const bool fast = (ctrl >> 16) != 0;
    const int hid  = j * 16 + ln;

    stage_weights(Wl, wih16, j, tid);

    float bias[4];
#pragma unroll
    for (int g = 0; g < 4; ++g) bias[g] = bsum[g * HID_ + hid];

    float c[2][4];
#pragma unroll
    for (int mt = 0; mt < 2; ++mt)
#pragma unroll
        for (int r = 0; r < 4; ++r) c[mt][r] = 0.f;

    const char* Bl = (const char*)Wl;
    const int tE = (qw ^ (ln & 7)) * 16;    // swizzled byte offset, kk-even

    __syncthreads();

    for (int t = 0; t < PH_; ++t) {
        const _Float16* xx = (t == 0) ? z16 : hs + (size_t)(t - 1) * BS_ * HID_;

        if (t >= 1) {
            if (tid == 0) {
                while (__hip_atomic_fetch_add(&cnt[C_STEP + ib * 32 + t - 1], 0,
                                              __ATOMIC_RELAXED,
                                              __HIP_MEMORY_SCOPE_AGENT) < 32) {
                    __builtin_amdgcn_s_sleep(1);
                }
                if (fast) __builtin_amdgcn_fence(__ATOMIC_ACQUIRE, "workgroup");
                else      __builtin_amdgcn_fence(__ATOMIC_ACQUIRE, "agent");
            }
            __syncthreads();
        }

        floatx4 acc[2][4];                  // bias pre-folded
#pragma unroll
        for (int mt = 0; mt < 2; ++mt)
#pragma unroll
            for (int g = 0; g < 4; ++g)
                acc[mt][g] = (floatx4){bias[g], bias[g], bias[g], bias[g]};

        // A fragment: A[m = ln][k = qw*8 + jj]; depth-4 global prefetch ring
        const _Float16* A0 = xx + (size_t)(ib * 256 + wv * 32 + ln) * HID_ + qw * 8;

        half8 a0r[4], a1r[4], bA[4], bB[4];
#pragma unroll
        for (int p = 0; p < 4; ++p) {
            a0r[p] = *(const half8*)(A0 + p * 32);
            a1r[p] = *(const half8*)(A0 + 16 * HID_ + p * 32);
        }
#pragma unroll
        for (int g = 0; g < 4; ++g)
            bA[g] = *(const half8*)(Bl + (g * 16 + ln) * 1024 + tE);

#pragma unroll
        for (int kk = 0; kk < 16; ++kk) {
            half8 ca0 = a0r[kk & 3], ca1 = a1r[kk & 3];
            if (kk < 12) {
                a0r[kk & 3] = *(const half8*)(A0 + (kk + 4) * 32);
                a1r[kk & 3] = *(const half8*)(A0 + 16 * HID_ + (kk + 4) * 32);
            }
            half8* cb = (kk & 1) ? bB : bA;
            half8* nb = (kk & 1) ? bA : bB;
            if (kk < 15) {
                int k1 = kk + 1;
#pragma unroll
                for (int g = 0; g < 4; ++g) {
                    int off = (g * 16 + ln) * 1024 + (k1 >> 1) * 128 + (tE ^ ((k1 & 1) << 6));
                    nb[g] = *(const half8*)(Bl + off);
                }
            }
#pragma unroll
            for (int g = 0; g < 4; ++g) {
                acc[0][g] = __builtin_amdgcn_mfma_f32_16x16x32_f16(ca0, cb[g], acc[0][g], 0, 0, 0);
                acc[1][g] = __builtin_amdgcn_mfma_f32_16x16x32_f16(ca1, cb[g], acc[1][g], 0, 0, 0);
            }
        }

        // epilogue: C/D layout col=ln, row=qw*4+r; all 4 gates in-thread
        _Float16* hb = hs + (size_t)t * BS_ * HID_
                          + (size_t)(ib * 256 + wv * 32 + qw * 4) * HID_ + hid;
#pragma unroll
        for (int mt = 0; mt < 2; ++mt) {
#pragma unroll
            for (int r = 0; r < 4; ++r) {
                float gi = acc[mt][0][r];
                float gf = acc[mt][1][r];
                float gg = acc[mt][2][r];
                float go = acc[mt][3][r];
                float cn = sigf(gf) * c[mt][r] + sigf(gi) * tanhfast(gg);
                float hn = sigf(go) * tanhfast(cn);
                c[mt][r] = cn;
                hb[(size_t)(mt * 16 + r) * HID_] = (_Float16)hn;
            }
        }

        // Barrier drains every wave's h-stores to the XCD L2 (vmcnt(0) before
        // s_barrier), then ONE thread signals.
        __syncthreads();
        if (t == 0) {
            if (tid == 0) {
                if (fast) {
                    __hip_atomic_fetch_add(&cnt[C_STEP + ib * 32], 1,
                                           __ATOMIC_RELAXED, __HIP_MEMORY_SCOPE_AGENT);
                } else {
                    __threadfence();
                    atomicAdd(&cnt[C_STEP + ib * 32], 1);
                }
            }
            stage_weights(Wl, wsum16, j, tid);   // switch to W_ih+W_hh
            __syncthreads();
        } else if (t < PH_ - 1) {
            if (tid == 0) {
                if (fast) {
                    __hip_atomic_fetch_add(&cnt[C_STEP + ib * 32 + t], 1,
                                           __ATOMIC_RELAXED, __HIP_MEMORY_SCOPE_AGENT);
                } else {
                    __threadfence();
                    atomicAdd(&cnt[C_STEP + ib * 32 + t], 1);
                }
            }
        }
    }
}

// ---------------------------------------------------------------------------
// y[b,t,:] = hs[t][b,:] @ W_d^T + b_d. One wave per (b,t) row.
// ---------------------------------------------------------------------------
__global__ __launch_bounds__(256) void dense_kernel(
    const _Float16* __restrict__ hs, const float* __restrict__ Wd,
    const float* __restrict__ bd, float* __restrict__ y)
{
    int gw   = (blockIdx.x * 256 + threadIdx.x) >> 6;   // wave id [0, 65536)
    int lane = threadIdx.x & 63;
    int tt = gw & 31, b = gw >> 5;
    half8 h = *(const half8*)(hs + ((size_t)tt * BS_ + b) * HID_ + lane * 8);
    float s0 = 0.f, s1 = 0.f;
#pragma unroll
    for (int k = 0; k < 8; ++k) {
        float hv = (float)h[k];
        s0 += hv * Wd[lane * 8 + k];
        s1 += hv * Wd[HID_ + lane * 8 + k];
    }
#pragma unroll
    for (int m = 32; m >= 1; m >>= 1) {
        s0 += __shfl_xor(s0, m);
        s1 += __shfl_xor(s1, m);
    }
    if (lane == 0) {
        float* o = y + ((size_t)b * PH_ + tt) * 2;
        o[0] = s0 + bd[0];
        o[1] = s1 + bd[1];
    }
}

// ---------------------------------------------------------------------------
extern "C" void kernel_launch(void* const* d_in, const int* in_sizes, int n_in,
                              void* d_out, int out_size, void* d_ws, size_t ws_size,
                              hipStream_t stream)
{
    (void)in_sizes; (void)n_in; (void)out_size; (void)ws_size;
    // setup_inputs order: hist(0, unused), z(1), W_ih(2), W_hh(3), b_ih(4),
    //                     b_hh(5), W_d(6), b_d(7)
    const float* z   = (const float*)d_in[1];
    const float* Wih = (const float*)d_in[2];
    const float* Whh = (const float*)d_in[3];
    const float* bih = (const float*)d_in[4];
    const float* bhh = (const float*)d_in[5];
    const float* Wd  = (const float*)d_in[6];
    const float* bd  = (const float*)d_in[7];
    float* y = (float*)d_out;

    char* ws = (char*)d_ws;
    _Float16* hs     = (_Float16*)ws;                          // 32*2048*512*2 = 64 MB
    _Float16* z16    = (_Float16*)(ws + (size_t)67108864);     // 2 MB
    _Float16* wih16  = (_Float16*)(ws + (size_t)69206016);     // 2 MB
    _Float16* wsum16 = (_Float16*)(ws + (size_t)71303168);     // 2 MB
    float*    bsum   = (float*)   (ws + (size_t)73400320);     // 8 KB
    int*      cnt    = (int*)     (ws + (size_t)73408512);     // C_TOTAL ints

    prep_kernel<<<4096, 256, 0, stream>>>(Wih, Whh, bih, bhh, z,
                                          wih16, wsum16, z16, bsum, cnt);

    {
        const void* k = (const void*)lstm_persist;
        void* args[] = {(void*)&wih16, (void*)&wsum16, (void*)&bsum,
                        (void*)&z16, (void*)&hs, (void*)&cnt};
        hipLaunchCooperativeKernel(k, dim3(256), dim3(512), args, 0, stream);
    }

    dense_kernel<<<16384, 256, 0, stream>>>(hs, Wd, bd, y);
}

// Round 6
// 462.679 us; speedup vs baseline: 1.0472x; 1.0472x over previous
//
#include <hip/hip_runtime.h>
#include <hip/hip_bf16.h>

#define BS_   2048
#define HID_  512
#define PH_   32

typedef _Float16 half8 __attribute__((ext_vector_type(8)));
typedef float floatx4 __attribute__((ext_vector_type(4)));

__device__ __forceinline__ float sigf(float x) { return 1.f / (1.f + __expf(-x)); }
__device__ __forceinline__ float tanhfast(float x) {
    float e = __expf(2.f * x);          // e=inf -> 1, e->0 -> -1 : safe at extremes
    return 1.f - 2.f / (e + 1.f);
}

// ---------------------------------------------------------------------------
// Prep: fp32 -> fp16 weights, combined weight W_ih+W_hh, combined bias, z16,
// zero the step counters.
// ---------------------------------------------------------------------------
__global__ __launch_bounds__(256) void prep_kernel(
    const float* __restrict__ Wih, const float* __restrict__ Whh,
    const float* __restrict__ bih, const float* __restrict__ bhh,
    const float* __restrict__ z,
    _Float16* __restrict__ wih16, _Float16* __restrict__ wsum16,
    _Float16* __restrict__ z16, float* __restrict__ bsum,
    int* __restrict__ cnt)
{
    int i = blockIdx.x * 256 + threadIdx.x;          // [0, 1048576)
    if (i < BS_ * HID_) z16[i] = (_Float16)z[i];
    if (i < 4 * HID_ * HID_) {
        float a = Wih[i];
        wih16[i]  = (_Float16)a;
        wsum16[i] = (_Float16)(a + Whh[i]);
    }
    if (i < 4 * HID_) bsum[i] = bih[i] + bhh[i];
    if (i < 256) cnt[i] = 0;
}

// ---------------------------------------------------------------------------
__device__ __forceinline__ void stage_weights(_Float16* Wl, const _Float16* Wg,
                                              int j, int tid)
{
#pragma unroll
    for (int rep = 0; rep < 8; ++rep) {
        int idx = rep * 512 + tid;      // [0, 4096) over (row n, 16B-block kb)
        int n  = idx >> 6;
        int kb = idx & 63;
        int g  = n >> 4, u = n & 15;
        const half8* src = (const half8*)(Wg + ((size_t)(g * HID_ + j * 16 + u)) * HID_ + kb * 8);
        int phys = (kb & 56) | ((kb & 7) ^ (n & 7));
        *(half8*)((char*)Wl + n * 1024 + phys * 16) = *src;
    }
}

// ---------------------------------------------------------------------------
// Persistent LSTM, one cooperative kernel for all 32 steps.
// Grid = 256 x 512.  ib = blockIdx & 7 (256-row batch tile), j = blockIdx >> 3
// (16 hidden units -> 64 gate rows). Weights in LDS (staged once per weight
// matrix); cell state in VGPRs.
//
// Hand-off protocol (NO fences, NO cache-ops — R3-R5's wbl2/inv storm cost
// ~6us/step and the L2-dirty-sharing fast path never engaged):
//   producer: h stores are AGENT-SCOPE (sc0+sc1) write-through — data lands
//     at the coherence point; the pre-barrier vmcnt(0) drain means they are
//     acked there before tid0 signals with a relaxed coherence-point RMW.
//   consumer: relaxed RMW poll (RMWs execute at the CP — R2 lesson: plain
//     acquire loads get served stale), then __syncthreads (compiler + exec
//     barrier) and PLAIN loads: this dispatch never cached h[t-1] addresses
//     in this XCD's L1/L2 before, so the miss pulls fresh CP data and
//     allocates it in L2 for the other 31 blocks of the group.
// ---------------------------------------------------------------------------
__global__ __launch_bounds__(512, 2) void lstm_persist(
    const _Float16* __restrict__ wih16, const _Float16* __restrict__ wsum16,
    const float* __restrict__ bsum, const _Float16* __restrict__ z16,
    _Float16* __restrict__ hs, int* __restrict__ cnt)
{
    __shared__ _Float16 Wl[64 * 512];   // 64 KB

    const int tid  = threadIdx.x;
    const int ib   = blockIdx.x & 7;
    const int j    = blockIdx.x >> 3;
    const int lane = tid & 63;
    const int wv   = tid >> 6;          // wave 0..7 -> M strip of 32 rows
    const int qw   = lane >> 4;         // quad 0..3
    const int ln   = lane & 15;
    const int hid  = j * 16 + ln;

    stage_weights(Wl, wih16, j, tid);

    float bias[4];
#pragma unroll
    for (int g = 0; g < 4; ++g) bias[g] = bsum[g * HID_ + hid];

    float c[2][4];
#pragma unroll
    for (int mt = 0; mt < 2; ++mt)
#pragma unroll
        for (int r = 0; r < 4; ++r) c[mt][r] = 0.f;

    const char* Bl = (const char*)Wl;
    const int tE = (qw ^ (ln & 7)) * 16;    // swizzled byte offset, kk-even

    __syncthreads();

    for (int t = 0; t < PH_; ++t) {
        const _Float16* xx = (t == 0) ? z16 : hs + (size_t)(t - 1) * BS_ * HID_;

        if (t >= 1) {
            if (tid == 0) {
                while (__hip_atomic_fetch_add(&cnt[ib * 32 + t - 1], 0,
                                              __ATOMIC_RELAXED,
                                              __HIP_MEMORY_SCOPE_AGENT) < 32) {
                    __builtin_amdgcn_s_sleep(1);
                }
            }
            __syncthreads();    // orders all following loads after the poll
        }

        floatx4 acc[2][4];                  // bias pre-folded
#pragma unroll
        for (int mt = 0; mt < 2; ++mt)
#pragma unroll
            for (int g = 0; g < 4; ++g)
                acc[mt][g] = (floatx4){bias[g], bias[g], bias[g], bias[g]};

        // A fragment: A[m = ln][k = qw*8 + jj]; depth-4 global prefetch ring
        const _Float16* A0 = xx + (size_t)(ib * 256 + wv * 32 + ln) * HID_ + qw * 8;

        half8 a0r[4], a1r[4], bA[4], bB[4];
#pragma unroll
        for (int p = 0; p < 4; ++p) {
            a0r[p] = *(const half8*)(A0 + p * 32);
            a1r[p] = *(const half8*)(A0 + 16 * HID_ + p * 32);
        }
#pragma unroll
        for (int g = 0; g < 4; ++g)
            bA[g] = *(const half8*)(Bl + (g * 16 + ln) * 1024 + tE);

#pragma unroll
        for (int kk = 0; kk < 16; ++kk) {
            half8 ca0 = a0r[kk & 3], ca1 = a1r[kk & 3];
            if (kk < 12) {
                a0r[kk & 3] = *(const half8*)(A0 + (kk + 4) * 32);
                a1r[kk & 3] = *(const half8*)(A0 + 16 * HID_ + (kk + 4) * 32);
            }
            half8* cb = (kk & 1) ? bB : bA;
            half8* nb = (kk & 1) ? bA : bB;
            if (kk < 15) {
                int k1 = kk + 1;
#pragma unroll
                for (int g = 0; g < 4; ++g) {
                    int off = (g * 16 + ln) * 1024 + (k1 >> 1) * 128 + (tE ^ ((k1 & 1) << 6));
                    nb[g] = *(const half8*)(Bl + off);
                }
            }
#pragma unroll
            for (int g = 0; g < 4; ++g) {
                acc[0][g] = __builtin_amdgcn_mfma_f32_16x16x32_f16(ca0, cb[g], acc[0][g], 0, 0, 0);
                acc[1][g] = __builtin_amdgcn_mfma_f32_16x16x32_f16(ca1, cb[g], acc[1][g], 0, 0, 0);
            }
        }

        // epilogue: C/D layout col=ln, row=qw*4+r; all 4 gates in-thread.
        // h stores are agent-scope write-through (land at the coherence point).
        _Float16* hb = hs + (size_t)t * BS_ * HID_
                          + (size_t)(ib * 256 + wv * 32 + qw * 4) * HID_ + hid;
#pragma unroll
        for (int mt = 0; mt < 2; ++mt) {
#pragma unroll
            for (int r = 0; r < 4; ++r) {
                float gi = acc[mt][0][r];
                float gf = acc[mt][1][r];
                float gg = acc[mt][2][r];
                float go = acc[mt][3][r];
                float cn = sigf(gf) * c[mt][r] + sigf(gi) * tanhfast(gg);
                float hn = sigf(go) * tanhfast(cn);
                c[mt][r] = cn;
                _Float16 hf = (_Float16)hn;
                short hv;
                __builtin_memcpy(&hv, &hf, 2);
                __hip_atomic_store((short*)(hb + (size_t)(mt * 16 + r) * HID_), hv,
                                   __ATOMIC_RELAXED, __HIP_MEMORY_SCOPE_AGENT);
            }
        }

        // Barrier drains every wave's stores (vmcnt(0) -> acked at the CP for
        // sc1 stores), then ONE relaxed CP-RMW signals the group.
        __syncthreads();
        if (t == 0) {
            if (tid == 0)
                __hip_atomic_fetch_add(&cnt[ib * 32], 1,
                                       __ATOMIC_RELAXED, __HIP_MEMORY_SCOPE_AGENT);
            stage_weights(Wl, wsum16, j, tid);   // switch to W_ih+W_hh
            __syncthreads();
        } else if (t < PH_ - 1) {
            if (tid == 0)
                __hip_atomic_fetch_add(&cnt[ib * 32 + t], 1,
                                       __ATOMIC_RELAXED, __HIP_MEMORY_SCOPE_AGENT);
        }
    }
}

// ---------------------------------------------------------------------------
// y[b,t,:] = hs[t][b,:] @ W_d^T + b_d. One wave per (b,t) row.
// ---------------------------------------------------------------------------
__global__ __launch_bounds__(256) void dense_kernel(
    const _Float16* __restrict__ hs, const float* __restrict__ Wd,
    const float* __restrict__ bd, float* __restrict__ y)
{
    int gw   = (blockIdx.x * 256 + threadIdx.x) >> 6;   // wave id [0, 65536)
    int lane = threadIdx.x & 63;
    int tt = gw & 31, b = gw >> 5;
    half8 h = *(const half8*)(hs + ((size_t)tt * BS_ + b) * HID_ + lane * 8);
    float s0 = 0.f, s1 = 0.f;
#pragma unroll
    for (int k = 0; k < 8; ++k) {
        float hv = (float)h[k];
        s0 += hv * Wd[lane * 8 + k];
        s1 += hv * Wd[HID_ + lane * 8 + k];
    }
#pragma unroll
    for (int m = 32; m >= 1; m >>= 1) {
        s0 += __shfl_xor(s0, m);
        s1 += __shfl_xor(s1, m);
    }
    if (lane == 0) {
        float* o = y + ((size_t)b * PH_ + tt) * 2;
        o[0] = s0 + bd[0];
        o[1] = s1 + bd[1];
    }
}

// ---------------------------------------------------------------------------
extern "C" void kernel_launch(void* const* d_in, const int* in_sizes, int n_in,
                              void* d_out, int out_size, void* d_ws, size_t ws_size,
                              hipStream_t stream)
{
    (void)in_sizes; (void)n_in; (void)out_size; (void)ws_size;
    // setup_inputs order: hist(0, unused), z(1), W_ih(2), W_hh(3), b_ih(4),
    //                     b_hh(5), W_d(6), b_d(7)
    const float* z   = (const float*)d_in[1];
    const float* Wih = (const float*)d_in[2];
    const float* Whh = (const float*)d_in[3];
    const float* bih = (const float*)d_in[4];
    const float* bhh = (const float*)d_in[5];
    const float* Wd  = (const float*)d_in[6];
    const float* bd  = (const float*)d_in[7];
    float* y = (float*)d_out;

    char* ws = (char*)d_ws;
    _Float16* hs     = (_Float16*)ws;                          // 32*2048*512*2 = 64 MB
    _Float16* z16    = (_Float16*)(ws + (size_t)67108864);     // 2 MB
    _Float16* wih16  = (_Float16*)(ws + (size_t)69206016);     // 2 MB
    _Float16* wsum16 = (_Float16*)(ws + (size_t)71303168);     // 2 MB
    float*    bsum   = (float*)   (ws + (size_t)73400320);     // 8 KB
    int*      cnt    = (int*)     (ws + (size_t)73408512);     // 256 ints

    prep_kernel<<<4096, 256, 0, stream>>>(Wih, Whh, bih, bhh, z,
                                          wih16, wsum16, z16, bsum, cnt);

    {
        const void* k = (const void*)lstm_persist;
        void* args[] = {(void*)&wih16, (void*)&wsum16, (void*)&bsum,
                        (void*)&z16, (void*)&hs, (void*)&cnt};
        hipLaunchCooperativeKernel(k, dim3(256), dim3(512), args, 0, stream);
    }

    dense_kernel<<<16384, 256, 0, stream>>>(hs, Wd, bd, y);
}